// Round 17
// baseline (42.716 us; speedup 1.0000x reference)
//
#include <hip/hip_runtime.h>

#define TPB 512
#define H 64
#define W 64

// t1: W-upsampled rows, T = 0..71 <-> input row r = T-4 (rows 0..3 / 68..71 zero pad)
#define NT1 72
#define T1S 132            // ==4 mod 32: b128 write / b64 col-read at bank minimum
#define T1_FLOATS (NT1 * T1S)   // 9504 floats = 38016 B
// t2: H-downsampled rows (64 x 128 + 4-col halos), ALIASES t1 (acc in regs across barrier)
#define T2S 140
#define T2_OFF 4
#define LDS_FLOATS T1_FLOATS    // 38016 B; occupancy is wave-capped (4 blocks/CU) not LDS-capped

typedef float v2f __attribute__((ext_vector_type(2)));

// v_pk_*_f32 packed fp32 (proven on-device rounds 4-16).
// op_sel[i] = src-i half for LOW result, op_sel_hi[i] = src-i half for HIGH result.
#define PKF_ACC_P(acc,a,b)  asm("v_pk_fma_f32 %0, %1, %2, %0 op_sel:[0,0,0] op_sel_hi:[1,1,1]" : "+v"(acc) : "v"(a), "v"(b))  // plain
#define PKF_ACC_A0(acc,a,b) asm("v_pk_fma_f32 %0, %1, %2, %0 op_sel:[0,0,0] op_sel_hi:[0,1,1]" : "+v"(acc) : "v"(a), "v"(b))  // src0 bcast lo
#define PKF_ACC_A1(acc,a,b) asm("v_pk_fma_f32 %0, %1, %2, %0 op_sel:[1,0,0] op_sel_hi:[1,1,1]" : "+v"(acc) : "v"(a), "v"(b))  // src0 bcast hi
#define PKF_ACC_B0(acc,a,b) asm("v_pk_fma_f32 %0, %1, %2, %0 op_sel:[0,0,0] op_sel_hi:[1,0,1]" : "+v"(acc) : "v"(a), "v"(b))  // src1 bcast lo
#define PKF_ACC_B1(acc,a,b) asm("v_pk_fma_f32 %0, %1, %2, %0 op_sel:[0,1,0] op_sel_hi:[1,1,1]" : "+v"(acc) : "v"(a), "v"(b))  // src1 bcast hi
#define PKF_NEW_B0(d,a,b,c) asm("v_pk_fma_f32 %0, %1, %2, %3 op_sel:[0,0,0] op_sel_hi:[1,0,1]" : "=v"(d) : "v"(a), "v"(b), "v"(c))
#define PKF_NEW_B1(d,a,b,c) asm("v_pk_fma_f32 %0, %1, %2, %3 op_sel:[0,1,0] op_sel_hi:[1,1,1]" : "=v"(d) : "v"(a), "v"(b), "v"(c))
#define PKM_P(d,a,b)        asm("v_pk_mul_f32 %0, %1, %2 op_sel:[0,0] op_sel_hi:[1,1]" : "=v"(d) : "v"(a), "v"(b))            // plain
#define PKM_A0(d,a,b)       asm("v_pk_mul_f32 %0, %1, %2 op_sel:[0,0] op_sel_hi:[0,1]" : "=v"(d) : "v"(a), "v"(b))            // src0 bcast lo
#define PKM_A1(d,a,b)       asm("v_pk_mul_f32 %0, %1, %2 op_sel:[1,0] op_sel_hi:[1,1]" : "=v"(d) : "v"(a), "v"(b))            // src0 bcast hi

__global__ __launch_bounds__(TPB, 6)
void afa_fused(const float* __restrict__ in, const float* __restrict__ bias,
               const float* __restrict__ upf, const float* __restrict__ dnf,
               float* __restrict__ out)
{
    __shared__ __align__(16) float lds[LDS_FLOATS];
    float* const s_t1 = lds;    // [72][132]
    float* const s_t2 = lds;    // [64][140], aliases t1 after cc loads complete

    const int tid = threadIdx.x;
    const int plane = blockIdx.x;            // 4096 blocks, one 64x64 plane each

    // ---- issue input loads FIRST: they fly during tap construction (block-start
    //      critical path was taps -> loads -> A; now loads overlap taps)
    const int r  = tid >> 3;
    const int cb = tid & 7;
    const float4* p4 = (const float4*)(in + (size_t)plane * (H * W) + r * W);
    float4 q0 = p4[cb == 0 ? 0 : 2 * cb - 1];
    const float4 q1 = p4[2 * cb];
    const float4 q2 = p4[2 * cb + 1];
    float4 q3 = p4[cb == 7 ? 15 : 2 * cb + 2];

    // taps. filt[0] = filt[11] = 0 structurally -> 5-tap up phases, 10-tap down.
    v2f gp[5], fh[5], fdp[5];
#pragma unroll
    for (int k = 0; k < 5; ++k) {
        gp[k]  = (v2f){2.0f * upf[9 - 2*k], 2.0f * upf[10 - 2*k]};
        fh[k]  = (v2f){1.41421356237309515f * dnf[2*k + 1], 1.41421356237309515f * dnf[2*k + 2]};
        fdp[k] = (v2f){dnf[10 - 2*k], dnf[9 - 2*k]};
    }
    const float bv = bias[plane & 511];
    const v2f b2  = (v2f){bv, bv};
    const v2f c02 = (v2f){0.2f, 0.2f};      // lrelu slope (sqrt2 folded into fh)
    const v2f z2  = (v2f){0.f, 0.f};

    // ---- zero t1 pad rows 0..3 and 68..71
    if (tid < 264) {
        *(float2*)(s_t1 + 2 * tid) = make_float2(0.f, 0.f);
        *(float2*)(s_t1 + 68 * T1S + 2 * tid) = make_float2(0.f, 0.f);
    }

    // ---- A: horizontal (W) x2 upsample -> t1. 512 units = (r 0..63, cb 0..7).
    {
        if (cb == 0) q0 = make_float4(0.f, 0.f, 0.f, 0.f);
        if (cb == 7) q3 = make_float4(0.f, 0.f, 0.f, 0.f);
        v2f wr2[6];                          // window x[8cb-2 .. 8cb+9] as 6 pairs
        wr2[0] = (v2f){q0.z, q0.w};
        wr2[1] = (v2f){q1.x, q1.y};  wr2[2] = (v2f){q1.z, q1.w};
        wr2[3] = (v2f){q2.x, q2.y};  wr2[4] = (v2f){q2.z, q2.w};
        wr2[5] = (v2f){q3.x, q3.y};
        v2f po[8];                           // po[q] = {o[2q], o[2q+1]}
#pragma unroll
        for (int q = 0; q < 8; ++q) {
            if (q & 1) { PKM_A1(po[q], wr2[q >> 1], gp[0]); }
            else       { PKM_A0(po[q], wr2[q >> 1], gp[0]); }
#pragma unroll
            for (int k = 1; k < 5; ++k) {
                if ((q + k) & 1) { PKF_ACC_A1(po[q], wr2[(q + k) >> 1], gp[k]); }
                else             { PKF_ACC_A0(po[q], wr2[(q + k) >> 1], gp[k]); }
            }
        }
        float* dst = s_t1 + (r + 4) * T1S + 16 * cb;
#pragma unroll
        for (int k = 0; k < 4; ++k)
            *(float4*)(dst + 4 * k) = make_float4(po[2*k][0], po[2*k][1], po[2*k+1][0], po[2*k+1][1]);
    }
    __syncthreads();

    // ---- fusedV loads ONLY (all t1 reads complete before bar2)
    const int c = tid & 63;
    const int q = tid >> 6;                  // wave-uniform
    v2f cc[16];
#pragma unroll
    for (int t = 0; t < 16; ++t)
        cc[t] = *(const v2f*)(s_t1 + (8 * q + t) * T1S + 2 * c);
    __syncthreads();   // all t1 reads done; t2 (aliased) may now be written

    // ---- t2 halo cols (early, off the critical path)
    {
        const int rw = tid >> 3, cz = tid & 7;     // 64 rows x 8 halo words
        s_t2[rw * T2S + (cz < 4 ? cz : 128 + cz)] = 0.f;
    }

    // ---- fusedV compute: H-up + bias + lrelu + H-down in registers (packed), then store.
    v2f accp[8] = {z2, z2, z2, z2, z2, z2, z2, z2};
    {
        const bool mlo = (q == 0);           // j = s-4 < 0      for t < 2
        const bool mhi = (q == 7);           // j = 108+s >= 128 for t >= 10
#pragma unroll
        for (int t = 0; t < 12; ++t) {
            // ir rows s=2t (taps gp.x) and s=2t+1 (taps gp.y), window cc[t..t+4]
            v2f ta, tb;
            PKF_NEW_B0(ta, cc[t], gp[0], b2);
            PKF_NEW_B1(tb, cc[t], gp[0], b2);
#pragma unroll
            for (int k = 1; k < 5; ++k) {
                PKF_ACC_B0(ta, cc[t + k], gp[k]);
                PKF_ACC_B1(tb, cc[t + k], gp[k]);
            }
            if (mlo && t < 2)   { ta = z2; tb = z2; }
            if (mhi && t >= 10) { ta = z2; tb = z2; }
            // lrelu (unscaled): r = max(x, 0.2x)  -- 3 ops/pair (PKM + 2 v_max)
            v2f ra, rb;
            PKM_P(ra, ta, c02);
            ra[0] = __builtin_fmaxf(ta[0], ra[0]);
            ra[1] = __builtin_fmaxf(ta[1], ra[1]);
            PKM_P(rb, tb, c02);
            rb[0] = __builtin_fmaxf(tb[0], rb[0]);
            rb[1] = __builtin_fmaxf(tb[1], rb[1]);
            // H-down accumulate: t2 row 8q+p <- ir rows s in [2p, 2p+9]; even s -> fh.y, odd s -> fh.x
#pragma unroll
            for (int p = 0; p < 8; ++p) {
                if (p <= t && t <= p + 4) {
                    const int m = 4 - (t - p);
                    PKF_ACC_B1(accp[p], ra, fh[m]);
                    PKF_ACC_B0(accp[p], rb, fh[m]);
                }
            }
        }
#pragma unroll
        for (int p = 0; p < 8; ++p)
            *(v2f*)(s_t2 + (8 * q + p) * T2S + T2_OFF + 2 * c) = accp[p];
    }
    __syncthreads();

    // ---- Wdown: horizontal (W) /2 downsample -> global. 1024 units, 2 per thread;
    //      both units' LDS loads hoisted ahead of both compute bodies.
    {
        const int oyA = tid >> 4,         oxbA = tid & 15;
        const int oyB = (tid + 512) >> 4, oxbB = tid & 15;
        const float* baseA = s_t2 + oyA * T2S + 8 * oxbA;   // float col 8oxb-4 (incl. T2_OFF)
        const float* baseB = s_t2 + oyB * T2S + 8 * oxbB;
        v2f WA[8], WB[8];
#pragma unroll
        for (int j = 0; j < 8; ++j) WA[j] = *(const v2f*)(baseA + 2 * j);
#pragma unroll
        for (int j = 0; j < 8; ++j) WB[j] = *(const v2f*)(baseB + 2 * j);
        float oA[4], oB[4];
#pragma unroll
        for (int p = 0; p < 4; ++p) {
            v2f accA, accB;
            PKM_P(accA, WA[p], fdp[0]);
            PKM_P(accB, WB[p], fdp[0]);
#pragma unroll
            for (int m = 1; m < 5; ++m) {
                PKF_ACC_P(accA, WA[p + m], fdp[m]);
                PKF_ACC_P(accB, WB[p + m], fdp[m]);
            }
            oA[p] = accA[0] + accA[1];
            oB[p] = accB[0] + accB[1];
        }
        float* poA = out + (size_t)plane * (H * W) + oyA * W + 4 * oxbA;
        float* poB = out + (size_t)plane * (H * W) + oyB * W + 4 * oxbB;
        *(float4*)poA = make_float4(oA[0], oA[1], oA[2], oA[3]);
        *(float4*)poB = make_float4(oB[0], oB[1], oB[2], oB[3]);
    }
}

extern "C" void kernel_launch(void* const* d_in, const int* in_sizes, int n_in,
                              void* d_out, int out_size, void* d_ws, size_t ws_size,
                              hipStream_t stream) {
    const float* in  = (const float*)d_in[0];
    const float* bv  = (const float*)d_in[1];
    const float* upf = (const float*)d_in[2];
    const float* dnf = (const float*)d_in[3];
    float* out = (float*)d_out;
    afa_fused<<<8 * 512, TPB, 0, stream>>>(in, bv, upf, dnf, out);
}

// Round 18
// 40.545 us; speedup vs baseline: 1.0535x; 1.0535x over previous
//
#include <hip/hip_runtime.h>

#define TPB 512
#define H 64
#define W 64

// t1: W-upsampled rows, T = 0..71 <-> input row r = T-4 (rows 0..3 / 68..71 zero pad)
#define NT1 72
#define T1S 132            // ==4 mod 32: b128 write / b64 col-read at bank minimum
#define T1_FLOATS (NT1 * T1S)   // 9504 floats = 38016 B
// t2: H-downsampled rows (64 x 128 + 4-col halos), ALIASES t1 (acc in regs across barrier)
#define T2S 140
#define T2_OFF 4
#define LDS_FLOATS T1_FLOATS    // 38016 B -> 4 blocks/CU (wave-capped)

typedef float v2f __attribute__((ext_vector_type(2)));

// v_pk_*_f32 packed fp32 (proven on-device rounds 4-17).
// op_sel[i] = src-i half for LOW result, op_sel_hi[i] = src-i half for HIGH result.
#define PKF_ACC_P(acc,a,b)  asm("v_pk_fma_f32 %0, %1, %2, %0 op_sel:[0,0,0] op_sel_hi:[1,1,1]" : "+v"(acc) : "v"(a), "v"(b))  // plain
#define PKF_ACC_A0(acc,a,b) asm("v_pk_fma_f32 %0, %1, %2, %0 op_sel:[0,0,0] op_sel_hi:[0,1,1]" : "+v"(acc) : "v"(a), "v"(b))  // src0 bcast lo
#define PKF_ACC_A1(acc,a,b) asm("v_pk_fma_f32 %0, %1, %2, %0 op_sel:[1,0,0] op_sel_hi:[1,1,1]" : "+v"(acc) : "v"(a), "v"(b))  // src0 bcast hi
#define PKF_ACC_B0(acc,a,b) asm("v_pk_fma_f32 %0, %1, %2, %0 op_sel:[0,0,0] op_sel_hi:[1,0,1]" : "+v"(acc) : "v"(a), "v"(b))  // src1 bcast lo
#define PKF_ACC_B1(acc,a,b) asm("v_pk_fma_f32 %0, %1, %2, %0 op_sel:[0,1,0] op_sel_hi:[1,1,1]" : "+v"(acc) : "v"(a), "v"(b))  // src1 bcast hi
#define PKF_NEW_B0(d,a,b,c) asm("v_pk_fma_f32 %0, %1, %2, %3 op_sel:[0,0,0] op_sel_hi:[1,0,1]" : "=v"(d) : "v"(a), "v"(b), "v"(c))
#define PKF_NEW_B1(d,a,b,c) asm("v_pk_fma_f32 %0, %1, %2, %3 op_sel:[0,1,0] op_sel_hi:[1,1,1]" : "=v"(d) : "v"(a), "v"(b), "v"(c))
#define PKM_P(d,a,b)        asm("v_pk_mul_f32 %0, %1, %2 op_sel:[0,0] op_sel_hi:[1,1]" : "=v"(d) : "v"(a), "v"(b))            // plain
#define PKM_A0(d,a,b)       asm("v_pk_mul_f32 %0, %1, %2 op_sel:[0,0] op_sel_hi:[0,1]" : "=v"(d) : "v"(a), "v"(b))            // src0 bcast lo
#define PKM_A1(d,a,b)       asm("v_pk_mul_f32 %0, %1, %2 op_sel:[1,0] op_sel_hi:[1,1]" : "=v"(d) : "v"(a), "v"(b))            // src0 bcast hi
#define PKM_B0(d,a,b)       asm("v_pk_mul_f32 %0, %1, %2 op_sel:[0,0] op_sel_hi:[1,0]" : "=v"(d) : "v"(a), "v"(b))            // src1 bcast lo

__global__ __launch_bounds__(TPB, 6)
void afa_fused(const float* __restrict__ in, const float* __restrict__ bias,
               const float* __restrict__ upf, const float* __restrict__ dnf,
               float* __restrict__ out)
{
    __shared__ __align__(16) float lds[LDS_FLOATS];
    float* const s_t1 = lds;    // [72][132]
    float* const s_t2 = lds;    // [64][140], aliases t1 after fusedV reads complete

    const int tid = threadIdx.x;
    const int plane = blockIdx.x;            // 4096 blocks, one 64x64 plane each

    // taps. filt[0] = filt[11] = 0 structurally -> 5-tap up phases, 10-tap down.
    // gp[k] = {2f[9-2k], 2f[10-2k]} ; fh[m] = {sqrt2*f[2m+1], sqrt2*f[2m+2]} (lrelu sqrt2 folded)
    // fdp[m] = {f[10-2m], f[9-2m]}  (W-down even/odd-tap pairs)
    v2f gp[5], fh[5], fdp[5];
#pragma unroll
    for (int k = 0; k < 5; ++k) {
        gp[k]  = (v2f){2.0f * upf[9 - 2*k], 2.0f * upf[10 - 2*k]};
        fh[k]  = (v2f){1.41421356237309515f * dnf[2*k + 1], 1.41421356237309515f * dnf[2*k + 2]};
        fdp[k] = (v2f){dnf[10 - 2*k], dnf[9 - 2*k]};
    }
    const float bv = bias[plane & 511];
    const v2f b2  = (v2f){bv, bv};
    const v2f cst = (v2f){0.6f, 0.4f};      // lrelu: 0.6x + 0.4|x| (sqrt2 folded into fh)
    const v2f z2  = (v2f){0.f, 0.f};

    // ---- zero t1 pad rows 0..3 and 68..71
    if (tid < 264) {
        *(float2*)(s_t1 + 2 * tid) = make_float2(0.f, 0.f);
        *(float2*)(s_t1 + 68 * T1S + 2 * tid) = make_float2(0.f, 0.f);
    }

    // ---- A: global load + horizontal (W) x2 upsample -> t1. 512 units = (r 0..63, cb 0..7).
    {
        const int r  = tid >> 3;
        const int cb = tid & 7;
        const float4* p4 = (const float4*)(in + (size_t)plane * (H * W) + r * W);
        float4 q0 = p4[cb == 0 ? 0 : 2 * cb - 1];
        const float4 q1 = p4[2 * cb];
        const float4 q2 = p4[2 * cb + 1];
        float4 q3 = p4[cb == 7 ? 15 : 2 * cb + 2];
        if (cb == 0) q0 = make_float4(0.f, 0.f, 0.f, 0.f);
        if (cb == 7) q3 = make_float4(0.f, 0.f, 0.f, 0.f);
        v2f wr2[6];                          // window x[8cb-2 .. 8cb+9] as 6 pairs
        wr2[0] = (v2f){q0.z, q0.w};
        wr2[1] = (v2f){q1.x, q1.y};  wr2[2] = (v2f){q1.z, q1.w};
        wr2[3] = (v2f){q2.x, q2.y};  wr2[4] = (v2f){q2.z, q2.w};
        wr2[5] = (v2f){q3.x, q3.y};
        v2f po[8];                           // po[q] = {o[2q], o[2q+1]}
#pragma unroll
        for (int q = 0; q < 8; ++q) {
            if (q & 1) { PKM_A1(po[q], wr2[q >> 1], gp[0]); }
            else       { PKM_A0(po[q], wr2[q >> 1], gp[0]); }
#pragma unroll
            for (int k = 1; k < 5; ++k) {
                if ((q + k) & 1) { PKF_ACC_A1(po[q], wr2[(q + k) >> 1], gp[k]); }
                else             { PKF_ACC_A0(po[q], wr2[(q + k) >> 1], gp[k]); }
            }
        }
        float* dst = s_t1 + (r + 4) * T1S + 16 * cb;
#pragma unroll
        for (int k = 0; k < 4; ++k)
            *(float4*)(dst + 4 * k) = make_float4(po[2*k][0], po[2*k][1], po[2*k+1][0], po[2*k+1][1]);
    }
    __syncthreads();

    // ---- fusedV: H-up + bias + lrelu + H-down in registers (packed over col-pairs).
    // 512 units = (col-pair c 0..63, group q 0..7); reads t1 rows 8q..8q+15.
    const int c = tid & 63;
    const int q = tid >> 6;                  // wave-uniform
    v2f accp[8] = {z2, z2, z2, z2, z2, z2, z2, z2};
    {
        v2f cc[16];
#pragma unroll
        for (int t = 0; t < 16; ++t)
            cc[t] = *(const v2f*)(s_t1 + (8 * q + t) * T1S + 2 * c);
        const bool mlo = (q == 0);           // j = s-4 < 0      for t < 2
        const bool mhi = (q == 7);           // j = 108+s >= 128 for t >= 10
#pragma unroll
        for (int t = 0; t < 12; ++t) {
            // ir rows s=2t (taps gp.x) and s=2t+1 (taps gp.y), window cc[t..t+4]
            v2f ta, tb;
            PKF_NEW_B0(ta, cc[t], gp[0], b2);
            PKF_NEW_B1(tb, cc[t], gp[0], b2);
#pragma unroll
            for (int k = 1; k < 5; ++k) {
                PKF_ACC_B0(ta, cc[t + k], gp[k]);
                PKF_ACC_B1(tb, cc[t + k], gp[k]);
            }
            if (mlo && t < 2)   { ta = z2; tb = z2; }
            if (mhi && t >= 10) { ta = z2; tb = z2; }
            // lrelu (unscaled): r = 0.6x + 0.4|x|
            v2f ra, aa, rb, ab;
            PKM_B0(ra, ta, cst);
            aa[0] = __builtin_fabsf(ta[0]); aa[1] = __builtin_fabsf(ta[1]);
            PKF_ACC_B1(ra, aa, cst);
            PKM_B0(rb, tb, cst);
            ab[0] = __builtin_fabsf(tb[0]); ab[1] = __builtin_fabsf(tb[1]);
            PKF_ACC_B1(rb, ab, cst);
            // H-down accumulate: t2 row 8q+p <- ir rows s in [2p, 2p+9]; even s -> fh.y, odd s -> fh.x
#pragma unroll
            for (int p = 0; p < 8; ++p) {
                if (p <= t && t <= p + 4) {
                    const int m = 4 - (t - p);
                    PKF_ACC_B1(accp[p], ra, fh[m]);
                    PKF_ACC_B0(accp[p], rb, fh[m]);
                }
            }
        }
    }
    __syncthreads();   // all t1 reads done; t2 may overwrite the aliased LDS

    // ---- store acc -> t2 + halo cols
#pragma unroll
    for (int p = 0; p < 8; ++p)
        *(v2f*)(s_t2 + (8 * q + p) * T2S + T2_OFF + 2 * c) = accp[p];
    {
        const int rw = tid >> 3, cz = tid & 7;     // 64 rows x 8 halo words
        s_t2[rw * T2S + (cz < 4 ? cz : 128 + cz)] = 0.f;
    }
    __syncthreads();

    // ---- Wdown: horizontal (W) /2 downsample -> global. 1024 units, 2 per thread.
    // o[p] = hadd( sum_m W[p+m] * fdp[m] ), W[j] = t2 col-pair {2j, 2j+1} of the unit window.
#pragma unroll
    for (int s_ = 0; s_ < 2; ++s_) {
        const int u = tid + 512 * s_;
        const int oy = u >> 4, oxb = u & 15;
        const float* base = s_t2 + oy * T2S + 8 * oxb;   // float col 8oxb-4 (incl. T2_OFF)
        v2f Wp[8];
#pragma unroll
        for (int j = 0; j < 8; ++j) Wp[j] = *(const v2f*)(base + 2 * j);
        float o2[4];
#pragma unroll
        for (int p = 0; p < 4; ++p) {
            v2f acc;
            PKM_P(acc, Wp[p], fdp[0]);
#pragma unroll
            for (int m = 1; m < 5; ++m)
                PKF_ACC_P(acc, Wp[p + m], fdp[m]);
            o2[p] = acc[0] + acc[1];
        }
        float* po = out + (size_t)plane * (H * W) + oy * W + 4 * oxb;
        *(float4*)po = make_float4(o2[0], o2[1], o2[2], o2[3]);
    }
}

extern "C" void kernel_launch(void* const* d_in, const int* in_sizes, int n_in,
                              void* d_out, int out_size, void* d_ws, size_t ws_size,
                              hipStream_t stream) {
    const float* in  = (const float*)d_in[0];
    const float* bv  = (const float*)d_in[1];
    const float* upf = (const float*)d_in[2];
    const float* dnf = (const float*)d_in[3];
    float* out = (float*)d_out;
    afa_fused<<<8 * 512, TPB, 0, stream>>>(in, bv, upf, dnf, out);
}